// Round 7
// baseline (139.084 us; speedup 1.0000x reference)
//
#include <hip/hip_runtime.h>
#include <stdint.h>

// ---------------------------------------------------------------------------
// Bottleneck with 3x3 local self-attention, MI355X (gfx950).
// R7: transpose fused INTO conv1 (x read once from HBM, no xt intermediate).
//   k_conv1_fused: block = 32 pixels x full M=256. K-loop stages w1 panel
//   (256x32 f32->bf16) and x tile (32c x 32P) transposed-on-LDS-write.
//   Grid 512 -> 2 blocks/CU. Old k_transpose_x / k_gemm_stream deleted.
// qkv (fused, persistent) / attn / conv3 (persistent + resid prefetch)
// unchanged from R6.
// Layout: activations (pix, C) bf16; 1x1 conv = gemm_bt:
//   D[o][P] = sum_k W[o][k] * Act[P][k], MFMA 16x16x32 bf16.
// ws (32 MiB): h1t@0 (att aliases after qkv), q@8MiB, k@16MiB, v@24MiB.
// ---------------------------------------------------------------------------

typedef __attribute__((ext_vector_type(4))) float f32x4;
typedef __attribute__((ext_vector_type(8))) __bf16 bf16x8;
typedef __attribute__((ext_vector_type(4))) unsigned short u16x4;
typedef __attribute__((ext_vector_type(8))) unsigned short u16x8;

__device__ __forceinline__ float bf2f(unsigned short u) {
  union { unsigned int i; float f; } c; c.i = ((unsigned int)u) << 16; return c.f;
}
__device__ __forceinline__ unsigned short f2bf(float f) {
  union { float f; unsigned int i; } c; c.f = f;
  unsigned int x = c.i;
  return (unsigned short)((x + 0x7FFFu + ((x >> 16) & 1u)) >> 16);
}

// ---------------------------------------------------------------------------
// conv1 with fused transpose. Block: 32 pixels (one image), full M=256.
// 4 waves, each 64 M-rows x 32 N; acc[4][2]. K=1024 in BK=32 steps.
// A: w1 (256x1024 f32) panel 256x32 -> bf16 LDS (row=o, swizzled col-groups).
// B: x (c-major f32) tile 32c x 32P, coalesced along P, transposed during the
//    bf16 LDS write into (P, c) with the same XOR group swizzle.
__global__ __launch_bounds__(256, 2) void k_conv1_fused(
    const float* __restrict__ x, const float* __restrict__ W,
    unsigned short* __restrict__ H, const float* __restrict__ scale,
    const float* __restrict__ bias) {
  __shared__ unsigned short lA[2][256 * 32];
  __shared__ unsigned short lB[2][32 * 32];
  const int n0 = blockIdx.x * 32;   // global pixel base (within one image)
  const int tid = threadIdx.x;
  const int lane = tid & 63, wid = tid >> 6;
  const int wm = wid * 64;
  const int fr = lane & 15, fq = lane >> 4;

  f32x4 acc[4][2] = {};

  // A staging: thread -> w1 row tid, 32 k-cols per step
  const float* Ag = W + (size_t)tid * 1024;
  // B staging: thread -> c-row tc = tid>>3, P-quad tpp = (tid&7)*4
  const int tc = tid >> 3, tpp = (tid & 7) * 4;
  const size_t xbase = (size_t)(n0 >> 10) * 1048576 + (n0 & 1023);

  f32x4 aw[8];
  f32x4 bx;
#pragma unroll
  for (int g = 0; g < 8; ++g) aw[g] = *(const f32x4*)(Ag + g * 4);
  bx = *(const f32x4*)&x[xbase + (size_t)tc * 1024 + tpp];

  int p = 0;
  for (int k0 = 0; k0 < 1024; k0 += 32, p ^= 1) {
    // pack + write current regs to LDS[p]
#pragma unroll
    for (int g = 0; g < 4; ++g) {
      u16x8 pk;
#pragma unroll
      for (int e = 0; e < 4; ++e) pk[e] = f2bf(aw[2 * g][e]);
#pragma unroll
      for (int e = 0; e < 4; ++e) pk[4 + e] = f2bf(aw[2 * g + 1][e]);
      *(u16x8*)&lA[p][tid * 32 + (g ^ (tid & 3)) * 8] = pk;
    }
#pragma unroll
    for (int u = 0; u < 4; ++u) {
      const int row = tpp + u;   // P-local
      lB[p][row * 32 + ((tc >> 3) ^ (row & 3)) * 8 + (tc & 7)] = f2bf(bx[u]);
    }
    if (k0 + 32 < 1024) {  // prefetch next K-step
#pragma unroll
      for (int g = 0; g < 8; ++g) aw[g] = *(const f32x4*)(Ag + k0 + 32 + g * 4);
      bx = *(const f32x4*)&x[xbase + (size_t)(k0 + 32 + tc) * 1024 + tpp];
    }
    __syncthreads();

    bf16x8 af[4], bb[2];
#pragma unroll
    for (int i = 0; i < 4; ++i) {
      const int row = wm + i * 16 + fr;
      af[i] = *(const bf16x8*)&lA[p][row * 32 + (fq ^ (row & 3)) * 8];
    }
#pragma unroll
    for (int j = 0; j < 2; ++j) {
      const int row = j * 16 + fr;
      bb[j] = *(const bf16x8*)&lB[p][row * 32 + (fq ^ (row & 3)) * 8];
    }
#pragma unroll
    for (int i = 0; i < 4; ++i)
#pragma unroll
      for (int j = 0; j < 2; ++j)
        acc[i][j] = __builtin_amdgcn_mfma_f32_16x16x32_bf16(af[i], bb[j], acc[i][j], 0, 0, 0);
  }

#pragma unroll
  for (int i = 0; i < 4; ++i) {
    const int ob = wm + i * 16 + fq * 4;
    const f32x4 s4 = *(const f32x4*)&scale[ob];
    const f32x4 b4 = *(const f32x4*)&bias[ob];
#pragma unroll
    for (int j = 0; j < 2; ++j) {
      const int P = n0 + j * 16 + fr;
      u16x4 pk;
#pragma unroll
      for (int rr = 0; rr < 4; ++rr) {
        float v = fmaxf(acc[i][j][rr] * s4[rr] + b4[rr], 0.0f);
        pk[rr] = f2bf(v);
      }
      *(u16x4*)&H[(size_t)P * 256 + ob] = pk;
    }
  }
}

// ---------------------------------------------------------------------------
// K=256 persistent gemm_bt. A-tile (64x256 bf16, 32KB) staged ONCE, swizzled.
// Block iterates NT n-tiles; B double-buffered with depth-2 reg prefetch.
// MODE 1 additionally prefetches the tile's 16 resid f32 at tile start.
// MODE 0 (fused qkv): seg = mt>>2 picks weights; out += seg*4Mi elems;
//                     relu for seg<2 (q,k), none for v.
// MODE 1 (conv3): f32 out with residual + relu, d_out[b][o][pix] layout.
template <int MODE, int NT>
__global__ __launch_bounds__(256, 4) void k_gemm_k256(
    const float* __restrict__ A0, const float* __restrict__ A1,
    const float* __restrict__ A2, const unsigned short* __restrict__ B,
    void* __restrict__ CoutV,
    const float* __restrict__ s0, const float* __restrict__ s1,
    const float* __restrict__ s2, const float* __restrict__ b0,
    const float* __restrict__ b1, const float* __restrict__ b2,
    const float* __restrict__ resid) {
  __shared__ unsigned short lA[64 * 256];
  __shared__ unsigned short lB[2][64 * 32];
  const int mt = blockIdx.y;
  int seg, m_loc, do_relu;
  const float *A, *sc, *bi;
  if (MODE == 0) {
    seg = mt >> 2; m_loc = (mt & 3) * 64;
    A  = seg == 0 ? A0 : (seg == 1 ? A1 : A2);
    sc = seg == 0 ? s0 : (seg == 1 ? s1 : s2);
    bi = seg == 0 ? b0 : (seg == 1 ? b1 : b2);
    do_relu = (seg < 2);
  } else {
    seg = 0; m_loc = mt * 64; A = A0; sc = s0; bi = b0; do_relu = 1;
  }
  const int tid = threadIdx.x;
  const int lane = tid & 63, wid = tid >> 6;
  const int wm = (wid >> 1) * 32, wn = (wid & 1) * 32;
  const int fr = lane & 15, fq = lane >> 4;

  // ---- stage A once: thread -> row rA=t>>2, quarter qd=t&3 (64 cols) ----
  {
    const int rA = tid >> 2, qd = tid & 3;
    const float* Ag = A + (size_t)(m_loc + rA) * 256 + qd * 64;
#pragma unroll
    for (int m = 0; m < 8; ++m) {
      f32x4 lo = *(const f32x4*)(Ag + m * 8);
      f32x4 hi = *(const f32x4*)(Ag + m * 8 + 4);
      u16x8 pk;
#pragma unroll
      for (int e = 0; e < 4; ++e) pk[e] = f2bf(lo[e]);
#pragma unroll
      for (int e = 0; e < 4; ++e) pk[4 + e] = f2bf(hi[e]);
      const int cg = qd * 8 + m;  // 0..31
      *(u16x8*)&lA[rA * 256 + (cg ^ ((rA & 7) << 2)) * 8] = pk;
    }
  }

  // ---- B staging setup ----
  const int rB = tid >> 2, gB = tid & 3;
  const int lofsB = rB * 32 + (gB ^ (rB & 3)) * 8;
  const int n0_blk = blockIdx.x * NT * 64;
  const unsigned short* Bg = B + (size_t)(n0_blk + rB) * 256 + gB * 8;

  u16x8 bvA = *(const u16x8*)(Bg);       // s = 0
  u16x8 bvB = *(const u16x8*)(Bg + 32);  // s = 1
  f32x4 acc[2][2] = {};
  float rres[2][2][4];
  int p = 0;
  const int TOT = NT * 8;

  for (int s = 0; s < TOT; ++s) {
    const int k0 = (s & 7) * 32;

    if (MODE == 1 && (s & 7) == 0) {  // prefetch this tile's resid early
      const int n0 = n0_blk + (s >> 3) * 64;
#pragma unroll
      for (int i = 0; i < 2; ++i) {
        const int ol = m_loc + wm + i * 16 + fq * 4;
#pragma unroll
        for (int j = 0; j < 2; ++j) {
          const int P = n0 + wn + j * 16 + fr;
          const size_t base = (size_t)(P >> 10) * 1048576 + (size_t)(P & 1023);
#pragma unroll
          for (int rr = 0; rr < 4; ++rr)
            rres[i][j][rr] = resid[base + (size_t)(ol + rr) * 1024];
        }
      }
    }

    *(u16x8*)&lB[p][lofsB] = bvA;
    bvA = bvB;
    if (s + 2 < TOT) {
      const int s2i = s + 2;
      bvB = *(const u16x8*)(Bg + (size_t)(s2i >> 3) * 16384 + (s2i & 7) * 32);
    }
    __syncthreads();

    bf16x8 af[2], bb[2];
#pragma unroll
    for (int i = 0; i < 2; ++i) {
      const int row = wm + i * 16 + fr;
      const int cg = (k0 >> 3) + fq;
      af[i] = *(const bf16x8*)&lA[row * 256 + (cg ^ ((row & 7) << 2)) * 8];
    }
#pragma unroll
    for (int j = 0; j < 2; ++j) {
      const int row = wn + j * 16 + fr;
      bb[j] = *(const bf16x8*)&lB[p][row * 32 + (fq ^ (row & 3)) * 8];
    }
#pragma unroll
    for (int i = 0; i < 2; ++i)
#pragma unroll
      for (int j = 0; j < 2; ++j)
        acc[i][j] = __builtin_amdgcn_mfma_f32_16x16x32_bf16(af[i], bb[j], acc[i][j], 0, 0, 0);
    p ^= 1;

    if ((s & 7) == 7) {  // tile epilogue (global IO only, no LDS)
      const int n0 = n0_blk + (s >> 3) * 64;
#pragma unroll
      for (int i = 0; i < 2; ++i) {
        const int ol = m_loc + wm + i * 16 + fq * 4;
        const f32x4 s4 = *(const f32x4*)&sc[ol];
        const f32x4 b4 = *(const f32x4*)&bi[ol];
#pragma unroll
        for (int j = 0; j < 2; ++j) {
          const int P = n0 + wn + j * 16 + fr;
          if (MODE == 0) {
            unsigned short* Cout = (unsigned short*)CoutV + (size_t)seg * 4194304;
            u16x4 pk;
#pragma unroll
            for (int rr = 0; rr < 4; ++rr) {
              float v = acc[i][j][rr] * s4[rr] + b4[rr];
              if (do_relu) v = fmaxf(v, 0.0f);
              pk[rr] = f2bf(v);
            }
            *(u16x4*)&Cout[(size_t)P * 256 + ol] = pk;
          } else {
            float* Cout = (float*)CoutV;
            const size_t base = (size_t)(P >> 10) * 1048576 + (size_t)(P & 1023);
#pragma unroll
            for (int rr = 0; rr < 4; ++rr) {
              float v = acc[i][j][rr] * s4[rr] + b4[rr] + rres[i][j][rr];
              Cout[base + (size_t)(ol + rr) * 1024] = fmaxf(v, 0.0f);
            }
          }
          acc[i][j] = (f32x4){0.f, 0.f, 0.f, 0.f};
        }
      }
    }
  }
}

// ---------------------------------------------------------------------------
// Local 3x3 attention. Thread = (pixel slot s=tid>>5, head g=tid&31).
__global__ __launch_bounds__(256, 4) void k_attn(
    const unsigned short* __restrict__ Q, const unsigned short* __restrict__ Kb,
    const unsigned short* __restrict__ Vb, unsigned short* __restrict__ O,
    const float* __restrict__ pos_h, const float* __restrict__ pos_w,
    const float* __restrict__ bs, const float* __restrict__ bb) {
  __shared__ float ph_l[3][256];
  __shared__ float pw_l[3][256];
  {
    const int c = threadIdx.x;
#pragma unroll
    for (int i = 0; i < 3; ++i) {
      ph_l[i][c] = pos_h[c * 3 + i];
      pw_l[i][c] = pos_w[c * 3 + i];
    }
  }
  __syncthreads();
  const int tid = threadIdx.x;
  const int g = tid & 31, s = tid >> 5;
  const int P = blockIdx.x * 8 + s;
  const int b = P >> 10, pix = P & 1023;
  const int hh = pix >> 5, ww = pix & 31;
  const int c0 = g * 8;

  float qf[8];
  {
    u16x8 qv = *(const u16x8*)&Q[(size_t)P * 256 + c0];
#pragma unroll
    for (int d = 0; d < 8; ++d) qf[d] = bf2f(qv[d]);
  }
  float Ai[3], Bj[3];
#pragma unroll
  for (int i = 0; i < 3; ++i) {
    float a = 0.f, w = 0.f;
#pragma unroll
    for (int d = 0; d < 8; ++d) {
      a += qf[d] * ph_l[i][c0 + d];
      w += qf[d] * pw_l[i][c0 + d];
    }
    Ai[i] = a; Bj[i] = w;
  }

  float S[9];
  int nPs[9];
#pragma unroll
  for (int t = 0; t < 9; ++t) {
    const int di = t / 3, dj = t % 3;
    const int nh = hh + di - 1, nw = ww + dj - 1;
    float sum = Ai[di] + Bj[dj];
    int nP = -1;
    if ((unsigned)nh < 32u && (unsigned)nw < 32u) {
      nP = (b << 10) + (nh << 5) + nw;
      u16x8 kv = *(const u16x8*)&Kb[(size_t)nP * 256 + c0];
#pragma unroll
      for (int d = 0; d < 8; ++d) sum += qf[d] * bf2f(kv[d]);
    }
    nPs[t] = nP;
    S[t] = sum;
  }

  float mx = S[0];
#pragma unroll
  for (int t = 1; t < 9; ++t) mx = fmaxf(mx, S[t]);
  float e[9], tot = 0.f;
#pragma unroll
  for (int t = 0; t < 9; ++t) { e[t] = __expf(S[t] - mx); tot += e[t]; }
  const float inv = 1.0f / tot;

  float of[8] = {0.f, 0.f, 0.f, 0.f, 0.f, 0.f, 0.f, 0.f};
#pragma unroll
  for (int t = 0; t < 9; ++t) {
    if (nPs[t] >= 0) {
      u16x8 vv = *(const u16x8*)&Vb[(size_t)nPs[t] * 256 + c0];
      const float w = e[t] * inv;
#pragma unroll
      for (int d = 0; d < 8; ++d) of[d] += w * bf2f(vv[d]);
    }
  }

  u16x8 res;
#pragma unroll
  for (int d = 0; d < 8; ++d) {
    float v = of[d] * bs[c0 + d] + bb[c0 + d];
    v = fmaxf(v, 0.0f);
    res[d] = f2bf(v);
  }
  *(u16x8*)&O[(size_t)P * 256 + c0] = res;
}

// ---------------------------------------------------------------------------
extern "C" void kernel_launch(void* const* d_in, const int* in_sizes, int n_in,
                              void* d_out, int out_size, void* d_ws, size_t ws_size,
                              hipStream_t stream) {
  (void)in_sizes; (void)n_in; (void)out_size; (void)ws_size;
  const float* x       = (const float*)d_in[0];
  const float* w1      = (const float*)d_in[1];
  const float* bn1_s   = (const float*)d_in[2];
  const float* bn1_b   = (const float*)d_in[3];
  const float* wq      = (const float*)d_in[4];
  const float* bnq_s   = (const float*)d_in[5];
  const float* bnq_b   = (const float*)d_in[6];
  const float* wk      = (const float*)d_in[7];
  const float* bnk_s   = (const float*)d_in[8];
  const float* bnk_b   = (const float*)d_in[9];
  const float* wv      = (const float*)d_in[10];
  const float* bnv_s   = (const float*)d_in[11];
  const float* bnv_b   = (const float*)d_in[12];
  const float* pos_h   = (const float*)d_in[13];
  const float* pos_w   = (const float*)d_in[14];
  const float* bnatt_s = (const float*)d_in[15];
  const float* bnatt_b = (const float*)d_in[16];
  const float* w3      = (const float*)d_in[17];
  const float* bn3_s   = (const float*)d_in[18];
  const float* bn3_b   = (const float*)d_in[19];

  char* ws = (char*)d_ws;
  unsigned short* h1t = (unsigned short*)(ws);
  unsigned short* qt  = (unsigned short*)(ws + 8388608);  // k @ +8MiB, v @ +16MiB
  unsigned short* att = h1t;

  // conv1 (+fused transpose): M=256, N=16384, K=1024; grid 512, 2 blocks/CU
  k_conv1_fused<<<dim3(512), dim3(256), 0, stream>>>(x, w1, h1t, bn1_s, bn1_b);

  // fused q,k,v: 12 m-tiles (4 per segment), 64 n-blocks x NT=4
  k_gemm_k256<0, 4><<<dim3(64, 12), dim3(256), 0, stream>>>(
      wq, wk, wv, h1t, qt, bnq_s, bnk_s, bnv_s, bnq_b, bnk_b, bnv_b, nullptr);

  k_attn<<<dim3(2048), dim3(256), 0, stream>>>(qt, qt + 4194304, qt + 8388608, att,
                                               pos_h, pos_w, bnatt_s, bnatt_b);

  // conv3 + residual + relu -> d_out (f32), M=1024, N=16384, K=256
  k_gemm_k256<1, 4><<<dim3(64, 16), dim3(256), 0, stream>>>(
      w3, nullptr, nullptr, att, d_out, bn3_s, nullptr, nullptr, bn3_b, nullptr,
      nullptr, x);
}

// Round 8
// 121.208 us; speedup vs baseline: 1.1475x; 1.1475x over previous
//
#include <hip/hip_runtime.h>
#include <stdint.h>

// ---------------------------------------------------------------------------
// Bottleneck with 3x3 local self-attention, MI355X (gfx950).
// R8: revert conv1 fusion (75us regression: latency-bound, staging bank
// conflicts, 512x w1 re-read). NEW: B-resident K=256 GEMM (k_gemm_n64):
// pixel tile (64 x 256, 32KB) staged in LDS ONCE; WEIGHTS streamed (w fits
// L2 -> re-reads ~free). Kills conv3's 16x att re-read through L3 and
// qkv's triple h1 read. qkv: grid(256,3), y=segment. conv3: grid(256,4).
// Layout: activations (pix, C) bf16; 1x1 conv = gemm_bt:
//   D[o][P] = sum_k W[o][k] * Act[P][k], MFMA 16x16x32 bf16.
// ws (32 MiB): h1t@0 (att aliases after qkv), q@8MiB, k@16MiB, v@24MiB.
// xt (32MiB bf16) staged in d_out's first half (f32 64MiB), dead before conv3.
// ---------------------------------------------------------------------------

typedef __attribute__((ext_vector_type(4))) float f32x4;
typedef __attribute__((ext_vector_type(8))) __bf16 bf16x8;
typedef __attribute__((ext_vector_type(4))) unsigned short u16x4;
typedef __attribute__((ext_vector_type(8))) unsigned short u16x8;

__device__ __forceinline__ float bf2f(unsigned short u) {
  union { unsigned int i; float f; } c; c.i = ((unsigned int)u) << 16; return c.f;
}
__device__ __forceinline__ unsigned short f2bf(float f) {
  union { float f; unsigned int i; } c; c.f = f;
  unsigned int x = c.i;
  return (unsigned short)((x + 0x7FFFu + ((x >> 16) & 1u)) >> 16);
}

// ---------------------------------------------------------------------------
// x (16,1024ch,1024pix) f32 -> xt (16,1024pix,1024ch) bf16, LDS tile transpose.
__global__ __launch_bounds__(256) void k_transpose_x(const float* __restrict__ x,
                                                     unsigned short* __restrict__ xt) {
  __shared__ float tile[32][33];
  const int b  = blockIdx.z;
  const int c0 = blockIdx.y * 32;
  const int p0 = blockIdx.x * 32;
  const int tx = threadIdx.x & 31;
  const int ty = threadIdx.x >> 5;  // 0..7
  const float* xb = x + (size_t)b * 1048576;
  unsigned short* xtb = xt + (size_t)b * 1048576;
#pragma unroll
  for (int i = 0; i < 4; ++i)
    tile[ty + i * 8][tx] = xb[(size_t)(c0 + ty + i * 8) * 1024 + p0 + tx];
  __syncthreads();
#pragma unroll
  for (int i = 0; i < 4; ++i)
    xtb[(size_t)(p0 + ty + i * 8) * 1024 + c0 + tx] = f2bf(tile[tx][ty + i * 8]);
}

// ---------------------------------------------------------------------------
// Streaming gemm_bt for conv1 (K=1024). 64x64 tile, BK=32, dbuf LDS,
// depth-2 register prefetch. (R6 version, measured-good.)
__global__ __launch_bounds__(256, 4) void k_gemm_stream(
    const float* __restrict__ A, const unsigned short* __restrict__ B,
    unsigned short* __restrict__ Cout, const float* __restrict__ scale,
    const float* __restrict__ bias, int K) {
  __shared__ unsigned short lA[2][64 * 32];
  __shared__ unsigned short lB[2][64 * 32];
  const int m0  = blockIdx.y * 64;
  const int n0  = blockIdx.x * 64;
  const int tid = threadIdx.x;
  const int lane = tid & 63;
  const int wid  = tid >> 6;
  const int wm = (wid >> 1) * 32, wn = (wid & 1) * 32;
  const int fr = lane & 15, fq = lane >> 4;

  f32x4 acc[2][2] = {};

  const int r = tid >> 2;
  const int g = tid & 3;
  const float*          Ag = A + (size_t)(m0 + r) * K + g * 8;
  const unsigned short* Bg = B + (size_t)(n0 + r) * K + g * 8;
  const int lofs = r * 32 + (g ^ (r & 3)) * 8;

  f32x4 aA[2], aB[2];
  u16x8 bvA, bvB;
  aA[0] = *(const f32x4*)(Ag);      aA[1] = *(const f32x4*)(Ag + 4);
  bvA   = *(const u16x8*)(Bg);
  aB[0] = *(const f32x4*)(Ag + 32); aB[1] = *(const f32x4*)(Ag + 36);
  bvB   = *(const u16x8*)(Bg + 32);

  int p = 0;
  for (int k0 = 0; k0 < K; k0 += 32, p ^= 1) {
    u16x8 ap;
#pragma unroll
    for (int i = 0; i < 8; ++i) ap[i] = f2bf(aA[i >> 2][i & 3]);
    *(u16x8*)&lA[p][lofs] = ap;
    *(u16x8*)&lB[p][lofs] = bvA;
    aA[0] = aB[0]; aA[1] = aB[1]; bvA = bvB;
    if (k0 + 64 < K) {
      aB[0] = *(const f32x4*)(Ag + k0 + 64);
      aB[1] = *(const f32x4*)(Ag + k0 + 68);
      bvB   = *(const u16x8*)(Bg + k0 + 64);
    }
    __syncthreads();

    bf16x8 af[2], bb[2];
#pragma unroll
    for (int i = 0; i < 2; ++i) {
      const int row = wm + i * 16 + fr;
      af[i] = *(const bf16x8*)&lA[p][row * 32 + (fq ^ (row & 3)) * 8];
    }
#pragma unroll
    for (int j = 0; j < 2; ++j) {
      const int row = wn + j * 16 + fr;
      bb[j] = *(const bf16x8*)&lB[p][row * 32 + (fq ^ (row & 3)) * 8];
    }
#pragma unroll
    for (int i = 0; i < 2; ++i)
#pragma unroll
      for (int j = 0; j < 2; ++j)
        acc[i][j] = __builtin_amdgcn_mfma_f32_16x16x32_bf16(af[i], bb[j], acc[i][j], 0, 0, 0);
  }

#pragma unroll
  for (int i = 0; i < 2; ++i) {
    const int ob = m0 + wm + i * 16 + fq * 4;
    const f32x4 s4 = *(const f32x4*)&scale[ob];
    const f32x4 b4 = *(const f32x4*)&bias[ob];
#pragma unroll
    for (int j = 0; j < 2; ++j) {
      const int P = n0 + wn + j * 16 + fr;
      u16x4 pk;
#pragma unroll
      for (int rr = 0; rr < 4; ++rr) {
        float v = fmaxf(acc[i][j][rr] * s4[rr] + b4[rr], 0.0f);
        pk[rr] = f2bf(v);
      }
      *(u16x4*)&Cout[(size_t)P * 256 + ob] = pk;
    }
  }
}

// ---------------------------------------------------------------------------
// B-resident K=256 gemm_bt. Pixel tile (64 x 256 bf16, 32KB) staged ONCE,
// swizzled cg^=(row&7)<<2. Weights (f32, L2-resident) streamed through a
// double-buffered 64x32 A-tile with register prefetch; 1 barrier/K-step.
// Block processes MT=4 m-tiles (TOT=32 steps). LDS 40KB -> 4 blocks/CU.
// MODE 0 (qkv): yy=blockIdx.y=segment {q,k,v}; out += seg*4Mi elems (pix-major
//               bf16); relu for seg<2.
// MODE 1 (conv3): A row base = yy*256; f32 out with residual + relu,
//               d_out[b][o][pix] layout; resid prefetched at m-tile start.
template <int MODE>
__global__ __launch_bounds__(256, 4) void k_gemm_n64(
    const float* __restrict__ A0, const float* __restrict__ A1,
    const float* __restrict__ A2, const unsigned short* __restrict__ B,
    void* __restrict__ CoutV,
    const float* __restrict__ s0, const float* __restrict__ s1,
    const float* __restrict__ s2, const float* __restrict__ b0,
    const float* __restrict__ b1, const float* __restrict__ b2,
    const float* __restrict__ resid) {
  __shared__ unsigned short lB[64 * 256];     // resident pixels x K
  __shared__ unsigned short lA[2][64 * 32];   // streamed weight tile (dbuf)
  const int n0 = blockIdx.x * 64;
  const int yy = blockIdx.y;
  int seg, do_relu, obase;
  const float *A, *sc, *bi;
  if (MODE == 0) {
    seg = yy; obase = 0;
    A  = yy == 0 ? A0 : (yy == 1 ? A1 : A2);
    sc = yy == 0 ? s0 : (yy == 1 ? s1 : s2);
    bi = yy == 0 ? b0 : (yy == 1 ? b1 : b2);
    do_relu = (yy < 2);
  } else {
    seg = 0; obase = yy * 256;
    A = A0 + (size_t)yy * 65536; sc = s0 + obase; bi = b0 + obase;
    do_relu = 1;
  }
  const int tid = threadIdx.x;
  const int lane = tid & 63, wid = tid >> 6;
  const int wm = (wid >> 1) * 32, wn = (wid & 1) * 32;
  const int fr = lane & 15, fq = lane >> 4;

  // ---- stage resident B (bf16 source, straight copies) ----
  {
    const int rB = tid >> 2, qd = tid & 3;
    const unsigned short* Bg = B + (size_t)(n0 + rB) * 256;
#pragma unroll
    for (int m = 0; m < 8; ++m) {
      u16x8 v = *(const u16x8*)(Bg + m * 32 + qd * 8);
      const int cg = m * 4 + qd;  // col-group 0..31
      *(u16x8*)&lB[rB * 256 + (cg ^ ((rB & 7) << 2)) * 8] = v;
    }
  }

  // ---- A streaming setup: thread -> row rA=t>>2 (0..63), group gA=t&3 ----
  const int rA = tid >> 2, gA = tid & 3;
  const int lofsA = rA * 32 + (gA ^ (rA & 3)) * 8;
  const float* Ag = A + (size_t)rA * 256 + gA * 8;

  f32x4 aw0 = *(const f32x4*)(Ag);
  f32x4 aw1 = *(const f32x4*)(Ag + 4);
  f32x4 acc[2][2] = {};
  float rres[2][2][4];
  int p = 0;
  const int TOT = 4 * 8;

  for (int s = 0; s < TOT; ++s) {
    const int mt = s >> 3, k0s = s & 7;

    if (MODE == 1 && k0s == 0) {  // prefetch this m-tile's resid early
#pragma unroll
      for (int i = 0; i < 2; ++i) {
        const int og = obase + mt * 64 + wm + i * 16 + fq * 4;
#pragma unroll
        for (int j = 0; j < 2; ++j) {
          const int P = n0 + wn + j * 16 + fr;
          const size_t base = (size_t)(P >> 10) * 1048576 + (size_t)(P & 1023);
#pragma unroll
          for (int rr = 0; rr < 4; ++rr)
            rres[i][j][rr] = resid[base + (size_t)(og + rr) * 1024];
        }
      }
    }

    // pack + write current A regs, prefetch next step's A
    {
      u16x8 ap;
#pragma unroll
      for (int i = 0; i < 8; ++i) ap[i] = f2bf((i < 4) ? aw0[i] : aw1[i - 4]);
      *(u16x8*)&lA[p][lofsA] = ap;
    }
    if (s + 1 < TOT) {
      const int s1i = s + 1;
      const size_t off = (size_t)((s1i >> 3) * 64) * 256 + (s1i & 7) * 32;
      aw0 = *(const f32x4*)(Ag + off);
      aw1 = *(const f32x4*)(Ag + off + 4);
    }
    __syncthreads();  // covers resident-B stage (s=0) and lA[p]

    bf16x8 af[2], bb[2];
#pragma unroll
    for (int i = 0; i < 2; ++i) {
      const int row = wm + i * 16 + fr;
      af[i] = *(const bf16x8*)&lA[p][row * 32 + (fq ^ (row & 3)) * 8];
    }
#pragma unroll
    for (int j = 0; j < 2; ++j) {
      const int row = wn + j * 16 + fr;
      const int cg = k0s * 4 + fq;
      bb[j] = *(const bf16x8*)&lB[row * 256 + (cg ^ ((row & 7) << 2)) * 8];
    }
#pragma unroll
    for (int i = 0; i < 2; ++i)
#pragma unroll
      for (int j = 0; j < 2; ++j)
        acc[i][j] = __builtin_amdgcn_mfma_f32_16x16x32_bf16(af[i], bb[j], acc[i][j], 0, 0, 0);
    p ^= 1;

    if (k0s == 7) {  // m-tile epilogue (global IO only, no LDS)
#pragma unroll
      for (int i = 0; i < 2; ++i) {
        const int ol = mt * 64 + wm + i * 16 + fq * 4;  // local o (0..255)
        const f32x4 s4 = *(const f32x4*)&sc[ol];
        const f32x4 b4 = *(const f32x4*)&bi[ol];
#pragma unroll
        for (int j = 0; j < 2; ++j) {
          const int P = n0 + wn + j * 16 + fr;
          if (MODE == 0) {
            unsigned short* Cout = (unsigned short*)CoutV + (size_t)seg * 4194304;
            u16x4 pk;
#pragma unroll
            for (int rr = 0; rr < 4; ++rr) {
              float v = acc[i][j][rr] * s4[rr] + b4[rr];
              if (do_relu) v = fmaxf(v, 0.0f);
              pk[rr] = f2bf(v);
            }
            *(u16x4*)&Cout[(size_t)P * 256 + ol] = pk;
          } else {
            float* Cout = (float*)CoutV;
            const int og = obase + ol;
            const size_t base = (size_t)(P >> 10) * 1048576 + (size_t)(P & 1023);
#pragma unroll
            for (int rr = 0; rr < 4; ++rr) {
              float v = acc[i][j][rr] * s4[rr] + b4[rr] + rres[i][j][rr];
              Cout[base + (size_t)(og + rr) * 1024] = fmaxf(v, 0.0f);
            }
          }
          acc[i][j] = (f32x4){0.f, 0.f, 0.f, 0.f};
        }
      }
    }
  }
}

// ---------------------------------------------------------------------------
// Local 3x3 attention. Thread = (pixel slot s=tid>>5, head g=tid&31).
__global__ __launch_bounds__(256, 4) void k_attn(
    const unsigned short* __restrict__ Q, const unsigned short* __restrict__ Kb,
    const unsigned short* __restrict__ Vb, unsigned short* __restrict__ O,
    const float* __restrict__ pos_h, const float* __restrict__ pos_w,
    const float* __restrict__ bs, const float* __restrict__ bb) {
  __shared__ float ph_l[3][256];
  __shared__ float pw_l[3][256];
  {
    const int c = threadIdx.x;
#pragma unroll
    for (int i = 0; i < 3; ++i) {
      ph_l[i][c] = pos_h[c * 3 + i];
      pw_l[i][c] = pos_w[c * 3 + i];
    }
  }
  __syncthreads();
  const int tid = threadIdx.x;
  const int g = tid & 31, s = tid >> 5;
  const int P = blockIdx.x * 8 + s;
  const int b = P >> 10, pix = P & 1023;
  const int hh = pix >> 5, ww = pix & 31;
  const int c0 = g * 8;

  float qf[8];
  {
    u16x8 qv = *(const u16x8*)&Q[(size_t)P * 256 + c0];
#pragma unroll
    for (int d = 0; d < 8; ++d) qf[d] = bf2f(qv[d]);
  }
  float Ai[3], Bj[3];
#pragma unroll
  for (int i = 0; i < 3; ++i) {
    float a = 0.f, w = 0.f;
#pragma unroll
    for (int d = 0; d < 8; ++d) {
      a += qf[d] * ph_l[i][c0 + d];
      w += qf[d] * pw_l[i][c0 + d];
    }
    Ai[i] = a; Bj[i] = w;
  }

  float S[9];
  int nPs[9];
#pragma unroll
  for (int t = 0; t < 9; ++t) {
    const int di = t / 3, dj = t % 3;
    const int nh = hh + di - 1, nw = ww + dj - 1;
    float sum = Ai[di] + Bj[dj];
    int nP = -1;
    if ((unsigned)nh < 32u && (unsigned)nw < 32u) {
      nP = (b << 10) + (nh << 5) + nw;
      u16x8 kv = *(const u16x8*)&Kb[(size_t)nP * 256 + c0];
#pragma unroll
      for (int d = 0; d < 8; ++d) sum += qf[d] * bf2f(kv[d]);
    }
    nPs[t] = nP;
    S[t] = sum;
  }

  float mx = S[0];
#pragma unroll
  for (int t = 1; t < 9; ++t) mx = fmaxf(mx, S[t]);
  float e[9], tot = 0.f;
#pragma unroll
  for (int t = 0; t < 9; ++t) { e[t] = __expf(S[t] - mx); tot += e[t]; }
  const float inv = 1.0f / tot;

  float of[8] = {0.f, 0.f, 0.f, 0.f, 0.f, 0.f, 0.f, 0.f};
#pragma unroll
  for (int t = 0; t < 9; ++t) {
    if (nPs[t] >= 0) {
      u16x8 vv = *(const u16x8*)&Vb[(size_t)nPs[t] * 256 + c0];
      const float w = e[t] * inv;
#pragma unroll
      for (int d = 0; d < 8; ++d) of[d] += w * bf2f(vv[d]);
    }
  }

  u16x8 res;
#pragma unroll
  for (int d = 0; d < 8; ++d) {
    float v = of[d] * bs[c0 + d] + bb[c0 + d];
    v = fmaxf(v, 0.0f);
    res[d] = f2bf(v);
  }
  *(u16x8*)&O[(size_t)P * 256 + c0] = res;
}

// ---------------------------------------------------------------------------
extern "C" void kernel_launch(void* const* d_in, const int* in_sizes, int n_in,
                              void* d_out, int out_size, void* d_ws, size_t ws_size,
                              hipStream_t stream) {
  (void)in_sizes; (void)n_in; (void)out_size; (void)ws_size;
  const float* x       = (const float*)d_in[0];
  const float* w1      = (const float*)d_in[1];
  const float* bn1_s   = (const float*)d_in[2];
  const float* bn1_b   = (const float*)d_in[3];
  const float* wq      = (const float*)d_in[4];
  const float* bnq_s   = (const float*)d_in[5];
  const float* bnq_b   = (const float*)d_in[6];
  const float* wk      = (const float*)d_in[7];
  const float* bnk_s   = (const float*)d_in[8];
  const float* bnk_b   = (const float*)d_in[9];
  const float* wv      = (const float*)d_in[10];
  const float* bnv_s   = (const float*)d_in[11];
  const float* bnv_b   = (const float*)d_in[12];
  const float* pos_h   = (const float*)d_in[13];
  const float* pos_w   = (const float*)d_in[14];
  const float* bnatt_s = (const float*)d_in[15];
  const float* bnatt_b = (const float*)d_in[16];
  const float* w3      = (const float*)d_in[17];
  const float* bn3_s   = (const float*)d_in[18];
  const float* bn3_b   = (const float*)d_in[19];

  char* ws = (char*)d_ws;
  unsigned short* h1t = (unsigned short*)(ws);
  unsigned short* qt  = (unsigned short*)(ws + 8388608);  // k @ +8MiB, v @ +16MiB
  unsigned short* att = h1t;
  unsigned short* xt  = (unsigned short*)d_out;

  k_transpose_x<<<dim3(32, 32, 16), dim3(256), 0, stream>>>(x, xt);

  // conv1: M=256, N=16384, K=1024
  k_gemm_stream<<<dim3(256, 4), dim3(256), 0, stream>>>(w1, xt, h1t, bn1_s, bn1_b, 1024);

  // fused q,k,v: B-resident; y = segment
  k_gemm_n64<0><<<dim3(256, 3), dim3(256), 0, stream>>>(
      wq, wk, wv, h1t, qt, bnq_s, bnk_s, bnv_s, bnq_b, bnk_b, bnv_b, nullptr);

  k_attn<<<dim3(2048), dim3(256), 0, stream>>>(qt, qt + 4194304, qt + 8388608, att,
                                               pos_h, pos_w, bnatt_s, bnatt_b);

  // conv3 + residual + relu -> d_out (f32); y = o-quarter (256 ch each)
  k_gemm_n64<1><<<dim3(256, 4), dim3(256), 0, stream>>>(
      w3, nullptr, nullptr, att, d_out, bn3_s, nullptr, nullptr, bn3_b, nullptr,
      nullptr, x);
}

// Round 9
// 112.371 us; speedup vs baseline: 1.2377x; 1.0786x over previous
//
#include <hip/hip_runtime.h>
#include <stdint.h>

// ---------------------------------------------------------------------------
// Bottleneck with 3x3 local self-attention, MI355X (gfx950).
// R9: all-bf16 GEMMs with global_load_lds (width 16) staging, zero staging
// VALU. Weights pre-converted once (w1 | stacked wq|wk|wv + stacked bn | w3).
// Unified k_gemm64<MODE>: m97-style 2-barrier loop, 64x64 tile, 4 waves.
//   MODE 0: bf16 pix-major out, per-256-row-segment relu mask (conv1, qkv).
//   MODE 1: conv3 f32 out + residual (prefetched) + relu.
// R8 lesson: never convert f32 in the K-loop staging path (VALU-bound).
// ws: h1t@0(8Mi) q|k|v@8Mi(24Mi) att@32Mi xt@40Mi(32Mi) w1b@72Mi wqkv@+.5Mi
//     w3b wsc/wbi; total <74MiB.
// ---------------------------------------------------------------------------

typedef __attribute__((ext_vector_type(4))) float f32x4;
typedef __attribute__((ext_vector_type(8))) __bf16 bf16x8;
typedef __attribute__((ext_vector_type(4))) unsigned short u16x4;
typedef __attribute__((ext_vector_type(8))) unsigned short u16x8;

__device__ __forceinline__ float bf2f(unsigned short u) {
  union { unsigned int i; float f; } c; c.i = ((unsigned int)u) << 16; return c.f;
}
__device__ __forceinline__ unsigned short f2bf(float f) {
  union { float f; unsigned int i; } c; c.f = f;
  unsigned int x = c.i;
  return (unsigned short)((x + 0x7FFFu + ((x >> 16) & 1u)) >> 16);
}
__device__ __forceinline__ void gload_lds16(const unsigned short* g, unsigned short* l) {
  __builtin_amdgcn_global_load_lds(
      (const __attribute__((address_space(1))) unsigned int*)(const void*)g,
      (__attribute__((address_space(3))) unsigned int*)(void*)l, 16, 0, 0);
}

// ---------------------------------------------------------------------------
// One-time weight conversion + bn stacking.
// [0,262144) w1 -> w1b ; [262144,458752) wq|wk|wv -> wqkvb ;
// [458752,720896) w3 -> w3b ; then 768 scales, 768 biases (f32 copies).
__global__ void k_convert(const float* __restrict__ w1, const float* __restrict__ wq,
                          const float* __restrict__ wk, const float* __restrict__ wv,
                          const float* __restrict__ w3,
                          const float* __restrict__ sq, const float* __restrict__ sk,
                          const float* __restrict__ sv, const float* __restrict__ bq,
                          const float* __restrict__ bk, const float* __restrict__ bv,
                          unsigned short* __restrict__ w1b, unsigned short* __restrict__ wqkvb,
                          unsigned short* __restrict__ w3b, float* __restrict__ sqkv,
                          float* __restrict__ bqkv) {
  const int idx = blockIdx.x * 256 + threadIdx.x;
  if (idx < 262144) { w1b[idx] = f2bf(w1[idx]); return; }
  if (idx < 327680) { wqkvb[idx - 262144] = f2bf(wq[idx - 262144]); return; }
  if (idx < 393216) { wqkvb[idx - 262144] = f2bf(wk[idx - 327680]); return; }
  if (idx < 458752) { wqkvb[idx - 262144] = f2bf(wv[idx - 393216]); return; }
  if (idx < 720896) { w3b[idx - 458752] = f2bf(w3[idx - 458752]); return; }
  if (idx < 721664) {
    const int i = idx - 720896;
    sqkv[i] = i < 256 ? sq[i] : (i < 512 ? sk[i - 256] : sv[i - 512]);
    return;
  }
  if (idx < 722432) {
    const int i = idx - 721664;
    bqkv[i] = i < 256 ? bq[i] : (i < 512 ? bk[i - 256] : bv[i - 512]);
  }
}

// ---------------------------------------------------------------------------
// x (16,1024ch,1024pix) f32 -> xt (16,1024pix,1024ch) bf16, LDS tile transpose.
__global__ __launch_bounds__(256) void k_transpose_x(const float* __restrict__ x,
                                                     unsigned short* __restrict__ xt) {
  __shared__ float tile[32][33];
  const int b  = blockIdx.z;
  const int c0 = blockIdx.y * 32;
  const int p0 = blockIdx.x * 32;
  const int tx = threadIdx.x & 31;
  const int ty = threadIdx.x >> 5;  // 0..7
  const float* xb = x + (size_t)b * 1048576;
  unsigned short* xtb = xt + (size_t)b * 1048576;
#pragma unroll
  for (int i = 0; i < 4; ++i)
    tile[ty + i * 8][tx] = xb[(size_t)(c0 + ty + i * 8) * 1024 + p0 + tx];
  __syncthreads();
#pragma unroll
  for (int i = 0; i < 4; ++i)
    xtb[(size_t)(p0 + ty + i * 8) * 1024 + c0 + tx] = f2bf(tile[tx][ty + i * 8]);
}

// ---------------------------------------------------------------------------
// Unified all-bf16 gemm_bt: D[o][P] = sum_k A[o][k]*B[P][k].
// A (M x K) bf16, B (N x K) bf16, both row-major. 64x64 tile, 4 waves (2x2),
// BK=32. m97 pattern: per step {2x global_load_lds(16B) per wave -> barrier
// -> 4x ds_read_b128 + 4x MFMA -> barrier}. LDS 8KB. No staging VALU.
// MODE 0: Cout u16: idx = (og>>8)*4194304 + P*256 + (og&255);
//         relu iff (relu_mask>>(og>>8))&1.   (conv1: mask=1; qkv: mask=3)
// MODE 1: Cout f32 d_out[b][o][pix] = relu(acc*s + b + resid); resid
//         prefetched to regs before the K-loop.
template <int MODE>
__global__ __launch_bounds__(256, 4) void k_gemm64(
    const unsigned short* __restrict__ A, const unsigned short* __restrict__ B,
    void* __restrict__ CoutV, const float* __restrict__ scale,
    const float* __restrict__ bias, const float* __restrict__ resid,
    int K, int relu_mask) {
  __shared__ unsigned short lA[64 * 32];
  __shared__ unsigned short lB[64 * 32];
  const int m0 = blockIdx.y * 64;
  const int n0 = blockIdx.x * 64;
  const int tid = threadIdx.x;
  const int lane = tid & 63, wid = tid >> 6;
  const int wm = (wid >> 1) * 32, wn = (wid & 1) * 32;
  const int fr = lane & 15, fq = lane >> 4;

  f32x4 acc[2][2] = {};

  // staging: wave w covers rows [w*16, w*16+16); lane l -> row w*16+(l>>2),
  // col (l&3)*8 .. +8. LDS dest is wave-uniform base (lane auto-offset 16B).
  const unsigned short* Asrc = A + (size_t)(m0 + wid * 16 + (lane >> 2)) * K + (lane & 3) * 8;
  const unsigned short* Bsrc = B + (size_t)(n0 + wid * 16 + (lane >> 2)) * K + (lane & 3) * 8;
  unsigned short* lAw = &lA[wid * 512];
  unsigned short* lBw = &lB[wid * 512];

  float rres[2][2][4];
  if (MODE == 1) {  // prefetch residual (consumed only in the epilogue)
#pragma unroll
    for (int i = 0; i < 2; ++i) {
      const int og = m0 + wm + i * 16 + fq * 4;
#pragma unroll
      for (int j = 0; j < 2; ++j) {
        const int P = n0 + wn + j * 16 + fr;
        const size_t base = (size_t)(P >> 10) * 1048576 + (size_t)(P & 1023);
#pragma unroll
        for (int rr = 0; rr < 4; ++rr)
          rres[i][j][rr] = resid[base + (size_t)(og + rr) * 1024];
      }
    }
  }

  for (int k0 = 0; k0 < K; k0 += 32) {
    gload_lds16(Asrc + k0, lAw);
    gload_lds16(Bsrc + k0, lBw);
    __syncthreads();  // compiler drains vmcnt before barrier -> tiles valid

    bf16x8 af[2], bb[2];
#pragma unroll
    for (int i = 0; i < 2; ++i)
      af[i] = *(const bf16x8*)&lA[(wm + i * 16 + fr) * 32 + fq * 8];
#pragma unroll
    for (int j = 0; j < 2; ++j)
      bb[j] = *(const bf16x8*)&lB[(wn + j * 16 + fr) * 32 + fq * 8];
#pragma unroll
    for (int i = 0; i < 2; ++i)
#pragma unroll
      for (int j = 0; j < 2; ++j)
        acc[i][j] = __builtin_amdgcn_mfma_f32_16x16x32_bf16(af[i], bb[j], acc[i][j], 0, 0, 0);
    __syncthreads();  // reads done before next overwrite
  }

#pragma unroll
  for (int i = 0; i < 2; ++i) {
    const int og = m0 + wm + i * 16 + fq * 4;   // stacked/global o, mult of 4
    const f32x4 s4 = *(const f32x4*)&scale[og];
    const f32x4 b4 = *(const f32x4*)&bias[og];
#pragma unroll
    for (int j = 0; j < 2; ++j) {
      const int P = n0 + wn + j * 16 + fr;
      if (MODE == 0) {
        unsigned short* Cout = (unsigned short*)CoutV;
        const int do_relu = (relu_mask >> (og >> 8)) & 1;
        const size_t obase = (size_t)(og >> 8) * 4194304 + (size_t)P * 256 + (og & 255);
        u16x4 pk;
#pragma unroll
        for (int rr = 0; rr < 4; ++rr) {
          float v = acc[i][j][rr] * s4[rr] + b4[rr];
          if (do_relu) v = fmaxf(v, 0.0f);
          pk[rr] = f2bf(v);
        }
        *(u16x4*)&Cout[obase] = pk;
      } else {
        float* Cout = (float*)CoutV;
        const size_t base = (size_t)(P >> 10) * 1048576 + (size_t)(P & 1023);
#pragma unroll
        for (int rr = 0; rr < 4; ++rr) {
          float v = acc[i][j][rr] * s4[rr] + b4[rr] + rres[i][j][rr];
          Cout[base + (size_t)(og + rr) * 1024] = fmaxf(v, 0.0f);
        }
      }
    }
  }
}

// ---------------------------------------------------------------------------
// Local 3x3 attention. Thread = (pixel slot s=tid>>5, head g=tid&31).
__global__ __launch_bounds__(256, 4) void k_attn(
    const unsigned short* __restrict__ Q, const unsigned short* __restrict__ Kb,
    const unsigned short* __restrict__ Vb, unsigned short* __restrict__ O,
    const float* __restrict__ pos_h, const float* __restrict__ pos_w,
    const float* __restrict__ bs, const float* __restrict__ bb) {
  __shared__ float ph_l[3][256];
  __shared__ float pw_l[3][256];
  {
    const int c = threadIdx.x;
#pragma unroll
    for (int i = 0; i < 3; ++i) {
      ph_l[i][c] = pos_h[c * 3 + i];
      pw_l[i][c] = pos_w[c * 3 + i];
    }
  }
  __syncthreads();
  const int tid = threadIdx.x;
  const int g = tid & 31, s = tid >> 5;
  const int P = blockIdx.x * 8 + s;
  const int b = P >> 10, pix = P & 1023;
  const int hh = pix >> 5, ww = pix & 31;
  const int c0 = g * 8;

  float qf[8];
  {
    u16x8 qv = *(const u16x8*)&Q[(size_t)P * 256 + c0];
#pragma unroll
    for (int d = 0; d < 8; ++d) qf[d] = bf2f(qv[d]);
  }
  float Ai[3], Bj[3];
#pragma unroll
  for (int i = 0; i < 3; ++i) {
    float a = 0.f, w = 0.f;
#pragma unroll
    for (int d = 0; d < 8; ++d) {
      a += qf[d] * ph_l[i][c0 + d];
      w += qf[d] * pw_l[i][c0 + d];
    }
    Ai[i] = a; Bj[i] = w;
  }

  float S[9];
  int nPs[9];
#pragma unroll
  for (int t = 0; t < 9; ++t) {
    const int di = t / 3, dj = t % 3;
    const int nh = hh + di - 1, nw = ww + dj - 1;
    float sum = Ai[di] + Bj[dj];
    int nP = -1;
    if ((unsigned)nh < 32u && (unsigned)nw < 32u) {
      nP = (b << 10) + (nh << 5) + nw;
      u16x8 kv = *(const u16x8*)&Kb[(size_t)nP * 256 + c0];
#pragma unroll
      for (int d = 0; d < 8; ++d) sum += qf[d] * bf2f(kv[d]);
    }
    nPs[t] = nP;
    S[t] = sum;
  }

  float mx = S[0];
#pragma unroll
  for (int t = 1; t < 9; ++t) mx = fmaxf(mx, S[t]);
  float e[9], tot = 0.f;
#pragma unroll
  for (int t = 0; t < 9; ++t) { e[t] = __expf(S[t] - mx); tot += e[t]; }
  const float inv = 1.0f / tot;

  float of[8] = {0.f, 0.f, 0.f, 0.f, 0.f, 0.f, 0.f, 0.f};
#pragma unroll
  for (int t = 0; t < 9; ++t) {
    if (nPs[t] >= 0) {
      u16x8 vv = *(const u16x8*)&Vb[(size_t)nPs[t] * 256 + c0];
      const float w = e[t] * inv;
#pragma unroll
      for (int d = 0; d < 8; ++d) of[d] += w * bf2f(vv[d]);
    }
  }

  u16x8 res;
#pragma unroll
  for (int d = 0; d < 8; ++d) {
    float v = of[d] * bs[c0 + d] + bb[c0 + d];
    v = fmaxf(v, 0.0f);
    res[d] = f2bf(v);
  }
  *(u16x8*)&O[(size_t)P * 256 + c0] = res;
}

// ---------------------------------------------------------------------------
extern "C" void kernel_launch(void* const* d_in, const int* in_sizes, int n_in,
                              void* d_out, int out_size, void* d_ws, size_t ws_size,
                              hipStream_t stream) {
  (void)in_sizes; (void)n_in; (void)out_size; (void)ws_size;
  const float* x       = (const float*)d_in[0];
  const float* w1      = (const float*)d_in[1];
  const float* bn1_s   = (const float*)d_in[2];
  const float* bn1_b   = (const float*)d_in[3];
  const float* wq      = (const float*)d_in[4];
  const float* bnq_s   = (const float*)d_in[5];
  const float* bnq_b   = (const float*)d_in[6];
  const float* wk      = (const float*)d_in[7];
  const float* bnk_s   = (const float*)d_in[8];
  const float* bnk_b   = (const float*)d_in[9];
  const float* wv      = (const float*)d_in[10];
  const float* bnv_s   = (const float*)d_in[11];
  const float* bnv_b   = (const float*)d_in[12];
  const float* pos_h   = (const float*)d_in[13];
  const float* pos_w   = (const float*)d_in[14];
  const float* bnatt_s = (const float*)d_in[15];
  const float* bnatt_b = (const float*)d_in[16];
  const float* w3      = (const float*)d_in[17];
  const float* bn3_s   = (const float*)d_in[18];
  const float* bn3_b   = (const float*)d_in[19];

  char* ws = (char*)d_ws;
  unsigned short* h1t   = (unsigned short*)(ws);               // 8 MiB
  unsigned short* qkvt  = (unsigned short*)(ws + 8388608);     // 24 MiB (q|k|v)
  unsigned short* att   = (unsigned short*)(ws + 33554432);    // 8 MiB
  unsigned short* xt    = (unsigned short*)(ws + 41943040);    // 32 MiB
  unsigned short* w1b   = (unsigned short*)(ws + 75497472);    // 512 KiB
  unsigned short* wqkvb = (unsigned short*)(ws + 76021760);    // 384 KiB
  unsigned short* w3b   = (unsigned short*)(ws + 76414976);    // 512 KiB
  float*          sqkv  = (float*)(ws + 76939264);             // 3 KiB
  float*          bqkv  = (float*)(ws + 76942336);             // 3 KiB

  k_convert<<<dim3(2822), dim3(256), 0, stream>>>(
      w1, wq, wk, wv, w3, bnq_s, bnk_s, bnv_s, bnq_b, bnk_b, bnv_b,
      w1b, wqkvb, w3b, sqkv, bqkv);

  k_transpose_x<<<dim3(32, 32, 16), dim3(256), 0, stream>>>(x, xt);

  // conv1: M=256, N=16384, K=1024 -> h1t (relu, mask bit0)
  k_gemm64<0><<<dim3(256, 4), dim3(256), 0, stream>>>(
      w1b, xt, h1t, bn1_s, bn1_b, nullptr, 1024, 1);

  // fused qkv: stacked A (768x256), M=768, N=16384, K=256 -> q|k|v
  k_gemm64<0><<<dim3(256, 12), dim3(256), 0, stream>>>(
      wqkvb, h1t, qkvt, sqkv, bqkv, nullptr, 256, 3);

  k_attn<<<dim3(2048), dim3(256), 0, stream>>>(
      qkvt, qkvt + 4194304, qkvt + 8388608, att, pos_h, pos_w, bnatt_s, bnatt_b);

  // conv3 + residual + relu -> d_out (f32), M=1024, N=16384, K=256
  k_gemm64<1><<<dim3(256, 16), dim3(256), 0, stream>>>(
      w3b, att, d_out, bn3_s, bn3_b, x, 256, 0);
}

// Round 10
// 109.603 us; speedup vs baseline: 1.2690x; 1.0253x over previous
//
#include <hip/hip_runtime.h>
#include <stdint.h>

// ---------------------------------------------------------------------------
// Bottleneck with 3x3 local self-attention, MI355X (gfx950).
// R10: bigger wave tiles via generic k_gemm_bt<MF,NF,MODE> (wave tile
// MF*16 x NF*16, 2x2 waves/block): conv1 64x128, qkv 128x128, conv3 128x64.
// gload_lds staging with PRE-SWIZZLED GLOBAL SOURCE (^(row&3) col-group) +
// matching swizzled ds_read (guide rule #21) -> 8-way LDS conflict -> 4-way.
// All-bf16 GEMMs (weights pre-converted once); conv3 resid prefetch before
// K-loop. R8 lesson kept: zero f32->bf16 conversion in GEMM hot loops.
// Layout: activations (pix, C) bf16; 1x1 conv = gemm_bt:
//   D[o][P] = sum_k A[o][k]*B[P][k], MFMA 16x16x32 bf16.
// ---------------------------------------------------------------------------

typedef __attribute__((ext_vector_type(4))) float f32x4;
typedef __attribute__((ext_vector_type(8))) __bf16 bf16x8;
typedef __attribute__((ext_vector_type(4))) unsigned short u16x4;
typedef __attribute__((ext_vector_type(8))) unsigned short u16x8;

__device__ __forceinline__ float bf2f(unsigned short u) {
  union { unsigned int i; float f; } c; c.i = ((unsigned int)u) << 16; return c.f;
}
__device__ __forceinline__ unsigned short f2bf(float f) {
  union { float f; unsigned int i; } c; c.f = f;
  unsigned int x = c.i;
  return (unsigned short)((x + 0x7FFFu + ((x >> 16) & 1u)) >> 16);
}
__device__ __forceinline__ void gload_lds16(const unsigned short* g, unsigned short* l) {
  __builtin_amdgcn_global_load_lds(
      (const __attribute__((address_space(1))) unsigned int*)(const void*)g,
      (__attribute__((address_space(3))) unsigned int*)(void*)l, 16, 0, 0);
}

// ---------------------------------------------------------------------------
// One-time weight conversion + bn stacking.
__global__ void k_convert(const float* __restrict__ w1, const float* __restrict__ wq,
                          const float* __restrict__ wk, const float* __restrict__ wv,
                          const float* __restrict__ w3,
                          const float* __restrict__ sq, const float* __restrict__ sk,
                          const float* __restrict__ sv, const float* __restrict__ bq,
                          const float* __restrict__ bk, const float* __restrict__ bv,
                          unsigned short* __restrict__ w1b, unsigned short* __restrict__ wqkvb,
                          unsigned short* __restrict__ w3b, float* __restrict__ sqkv,
                          float* __restrict__ bqkv) {
  const int idx = blockIdx.x * 256 + threadIdx.x;
  if (idx < 262144) { w1b[idx] = f2bf(w1[idx]); return; }
  if (idx < 327680) { wqkvb[idx - 262144] = f2bf(wq[idx - 262144]); return; }
  if (idx < 393216) { wqkvb[idx - 262144] = f2bf(wk[idx - 327680]); return; }
  if (idx < 458752) { wqkvb[idx - 262144] = f2bf(wv[idx - 393216]); return; }
  if (idx < 720896) { w3b[idx - 458752] = f2bf(w3[idx - 458752]); return; }
  if (idx < 721664) {
    const int i = idx - 720896;
    sqkv[i] = i < 256 ? sq[i] : (i < 512 ? sk[i - 256] : sv[i - 512]);
    return;
  }
  if (idx < 722432) {
    const int i = idx - 721664;
    bqkv[i] = i < 256 ? bq[i] : (i < 512 ? bk[i - 256] : bv[i - 512]);
  }
}

// ---------------------------------------------------------------------------
// x (16,1024ch,1024pix) f32 -> xt (16,1024pix,1024ch) bf16, LDS tile transpose.
__global__ __launch_bounds__(256) void k_transpose_x(const float* __restrict__ x,
                                                     unsigned short* __restrict__ xt) {
  __shared__ float tile[32][33];
  const int b  = blockIdx.z;
  const int c0 = blockIdx.y * 32;
  const int p0 = blockIdx.x * 32;
  const int tx = threadIdx.x & 31;
  const int ty = threadIdx.x >> 5;  // 0..7
  const float* xb = x + (size_t)b * 1048576;
  unsigned short* xtb = xt + (size_t)b * 1048576;
#pragma unroll
  for (int i = 0; i < 4; ++i)
    tile[ty + i * 8][tx] = xb[(size_t)(c0 + ty + i * 8) * 1024 + p0 + tx];
  __syncthreads();
#pragma unroll
  for (int i = 0; i < 4; ++i)
    xtb[(size_t)(p0 + ty + i * 8) * 1024 + c0 + tx] = f2bf(tile[tx][ty + i * 8]);
}

// ---------------------------------------------------------------------------
// Generic all-bf16 gemm_bt. Wave tile = MF*16 x NF*16; block = 2x2 waves ->
// BM=MF*32, BN=NF*32. BK=32. Per K-step per wave: MF/2+NF/2 gload_lds(16B),
// MF+NF ds_read_b128, MF*NF MFMA, 2 barriers. LDS linear; source col-group
// pre-swizzled by ^(row&3), read with cg = fq^(fr&3) (involution, rule #21).
// MODE 0: Cout u16 pix-major: idx=(og>>8)*4194304 + P*256 + (og&255);
//         relu iff (relu_mask>>(og>>8))&1.
// MODE 1: Cout f32 d_out[b][o][pix] = relu(acc*s+b+resid); resid prefetched
//         before the K-loop.
template <int MF, int NF, int MODE>
__global__ __launch_bounds__(256, 3) void k_gemm_bt(
    const unsigned short* __restrict__ A, const unsigned short* __restrict__ B,
    void* __restrict__ CoutV, const float* __restrict__ scale,
    const float* __restrict__ bias, const float* __restrict__ resid,
    int K, int relu_mask) {
  constexpr int BM = MF * 32, BN = NF * 32;
  __shared__ unsigned short lA[BM * 32];
  __shared__ unsigned short lB[BN * 32];
  const int m0 = blockIdx.y * BM;
  const int n0 = blockIdx.x * BN;
  const int tid = threadIdx.x;
  const int lane = tid & 63, wid = tid >> 6;
  const int wm = (wid >> 1) * (MF * 16), wn = (wid & 1) * (NF * 16);
  const int fr = lane & 15, fq = lane >> 4;
  const int cgr = (fq ^ (fr & 3)) * 8;   // swizzled read col offset (elems)

  f32x4 acc[MF][NF] = {};

  // staging: lane l -> LDS row base+(l>>2), col-group l&3 (linear dest);
  // source col-group pre-swizzled so LDS[row][cg] = global[row][cg^(row&3)].
  const int sr  = lane >> 2;
  const int scg = ((lane & 3) ^ (sr & 3)) * 8;
  const int warA = wid * (MF * 8);   // wave A-row base (rows per wave = BM/4)
  const int warB = wid * (NF * 8);
  const unsigned short* Asrc = A + (size_t)(m0 + warA + sr) * K + scg;
  const unsigned short* Bsrc = B + (size_t)(n0 + warB + sr) * K + scg;
  unsigned short* lAw = &lA[warA * 32];
  unsigned short* lBw = &lB[warB * 32];

  float rres[MF][NF][4];
  if (MODE == 1) {  // prefetch residual; consumed only in the epilogue
#pragma unroll
    for (int i = 0; i < MF; ++i) {
      const int og = m0 + wm + i * 16 + fq * 4;
#pragma unroll
      for (int j = 0; j < NF; ++j) {
        const int P = n0 + wn + j * 16 + fr;
        const size_t base = (size_t)(P >> 10) * 1048576 + (size_t)(P & 1023);
#pragma unroll
        for (int rr = 0; rr < 4; ++rr)
          rres[i][j][rr] = resid[base + (size_t)(og + rr) * 1024];
      }
    }
  }

  for (int k0 = 0; k0 < K; k0 += 32) {
#pragma unroll
    for (int u = 0; u < MF / 2; ++u)
      gload_lds16(Asrc + (size_t)u * 16 * K + k0, lAw + u * 512);
#pragma unroll
    for (int u = 0; u < NF / 2; ++u)
      gload_lds16(Bsrc + (size_t)u * 16 * K + k0, lBw + u * 512);
    __syncthreads();  // compiler drains vmcnt before barrier -> tiles valid

    bf16x8 af[MF], bb[NF];
#pragma unroll
    for (int i = 0; i < MF; ++i)
      af[i] = *(const bf16x8*)&lA[(wm + i * 16 + fr) * 32 + cgr];
#pragma unroll
    for (int j = 0; j < NF; ++j)
      bb[j] = *(const bf16x8*)&lB[(wn + j * 16 + fr) * 32 + cgr];
#pragma unroll
    for (int i = 0; i < MF; ++i)
#pragma unroll
      for (int j = 0; j < NF; ++j)
        acc[i][j] = __builtin_amdgcn_mfma_f32_16x16x32_bf16(af[i], bb[j], acc[i][j], 0, 0, 0);
    __syncthreads();  // reads done before next overwrite
  }

#pragma unroll
  for (int i = 0; i < MF; ++i) {
    const int og = m0 + wm + i * 16 + fq * 4;   // stacked/global o, mult of 4
    const f32x4 s4 = *(const f32x4*)&scale[og];
    const f32x4 b4 = *(const f32x4*)&bias[og];
#pragma unroll
    for (int j = 0; j < NF; ++j) {
      const int P = n0 + wn + j * 16 + fr;
      if (MODE == 0) {
        unsigned short* Cout = (unsigned short*)CoutV;
        const int do_relu = (relu_mask >> (og >> 8)) & 1;
        const size_t obase = (size_t)(og >> 8) * 4194304 + (size_t)P * 256 + (og & 255);
        u16x4 pk;
#pragma unroll
        for (int rr = 0; rr < 4; ++rr) {
          float v = acc[i][j][rr] * s4[rr] + b4[rr];
          if (do_relu) v = fmaxf(v, 0.0f);
          pk[rr] = f2bf(v);
        }
        *(u16x4*)&Cout[obase] = pk;
      } else {
        float* Cout = (float*)CoutV;
        const size_t base = (size_t)(P >> 10) * 1048576 + (size_t)(P & 1023);
#pragma unroll
        for (int rr = 0; rr < 4; ++rr) {
          float v = acc[i][j][rr] * s4[rr] + b4[rr] + rres[i][j][rr];
          Cout[base + (size_t)(og + rr) * 1024] = fmaxf(v, 0.0f);
        }
      }
    }
  }
}

// ---------------------------------------------------------------------------
// Local 3x3 attention. Thread = (pixel slot s=tid>>5, head g=tid&31).
__global__ __launch_bounds__(256, 4) void k_attn(
    const unsigned short* __restrict__ Q, const unsigned short* __restrict__ Kb,
    const unsigned short* __restrict__ Vb, unsigned short* __restrict__ O,
    const float* __restrict__ pos_h, const float* __restrict__ pos_w,
    const float* __restrict__ bs, const float* __restrict__ bb) {
  __shared__ float ph_l[3][256];
  __shared__ float pw_l[3][256];
  {
    const int c = threadIdx.x;
#pragma unroll
    for (int i = 0; i < 3; ++i) {
      ph_l[i][c] = pos_h[c * 3 + i];
      pw_l[i][c] = pos_w[c * 3 + i];
    }
  }
  __syncthreads();
  const int tid = threadIdx.x;
  const int g = tid & 31, s = tid >> 5;
  const int P = blockIdx.x * 8 + s;
  const int b = P >> 10, pix = P & 1023;
  const int hh = pix >> 5, ww = pix & 31;
  const int c0 = g * 8;

  float qf[8];
  {
    u16x8 qv = *(const u16x8*)&Q[(size_t)P * 256 + c0];
#pragma unroll
    for (int d = 0; d < 8; ++d) qf[d] = bf2f(qv[d]);
  }
  float Ai[3], Bj[3];
#pragma unroll
  for (int i = 0; i < 3; ++i) {
    float a = 0.f, w = 0.f;
#pragma unroll
    for (int d = 0; d < 8; ++d) {
      a += qf[d] * ph_l[i][c0 + d];
      w += qf[d] * pw_l[i][c0 + d];
    }
    Ai[i] = a; Bj[i] = w;
  }

  float S[9];
  int nPs[9];
#pragma unroll
  for (int t = 0; t < 9; ++t) {
    const int di = t / 3, dj = t % 3;
    const int nh = hh + di - 1, nw = ww + dj - 1;
    float sum = Ai[di] + Bj[dj];
    int nP = -1;
    if ((unsigned)nh < 32u && (unsigned)nw < 32u) {
      nP = (b << 10) + (nh << 5) + nw;
      u16x8 kv = *(const u16x8*)&Kb[(size_t)nP * 256 + c0];
#pragma unroll
      for (int d = 0; d < 8; ++d) sum += qf[d] * bf2f(kv[d]);
    }
    nPs[t] = nP;
    S[t] = sum;
  }

  float mx = S[0];
#pragma unroll
  for (int t = 1; t < 9; ++t) mx = fmaxf(mx, S[t]);
  float e[9], tot = 0.f;
#pragma unroll
  for (int t = 0; t < 9; ++t) { e[t] = __expf(S[t] - mx); tot += e[t]; }
  const float inv = 1.0f / tot;

  float of[8] = {0.f, 0.f, 0.f, 0.f, 0.f, 0.f, 0.f, 0.f};
#pragma unroll
  for (int t = 0; t < 9; ++t) {
    if (nPs[t] >= 0) {
      u16x8 vv = *(const u16x8*)&Vb[(size_t)nPs[t] * 256 + c0];
      const float w = e[t] * inv;
#pragma unroll
      for (int d = 0; d < 8; ++d) of[d] += w * bf2f(vv[d]);
    }
  }

  u16x8 res;
#pragma unroll
  for (int d = 0; d < 8; ++d) {
    float v = of[d] * bs[c0 + d] + bb[c0 + d];
    v = fmaxf(v, 0.0f);
    res[d] = f2bf(v);
  }
  *(u16x8*)&O[(size_t)P * 256 + c0] = res;
}

// ---------------------------------------------------------------------------
extern "C" void kernel_launch(void* const* d_in, const int* in_sizes, int n_in,
                              void* d_out, int out_size, void* d_ws, size_t ws_size,
                              hipStream_t stream) {
  (void)in_sizes; (void)n_in; (void)out_size; (void)ws_size;
  const float* x       = (const float*)d_in[0];
  const float* w1      = (const float*)d_in[1];
  const float* bn1_s   = (const float*)d_in[2];
  const float* bn1_b   = (const float*)d_in[3];
  const float* wq      = (const float*)d_in[4];
  const float* bnq_s   = (const float*)d_in[5];
  const float* bnq_b   = (const float*)d_in[6];
  const float* wk      = (const float*)d_in[7];
  const float* bnk_s   = (const float*)d_in[8];
  const float* bnk_b   = (const float*)d_in[9];
  const float* wv      = (const float*)d_in[10];
  const float* bnv_s   = (const float*)d_in[11];
  const float* bnv_b   = (const float*)d_in[12];
  const float* pos_h   = (const float*)d_in[13];
  const float* pos_w   = (const float*)d_in[14];
  const float* bnatt_s = (const float*)d_in[15];
  const float* bnatt_b = (const float*)d_in[16];
  const float* w3      = (const float*)d_in[17];
  const float* bn3_s   = (const float*)d_in[18];
  const float* bn3_b   = (const float*)d_in[19];

  char* ws = (char*)d_ws;
  unsigned short* h1t   = (unsigned short*)(ws);               // 8 MiB
  unsigned short* qkvt  = (unsigned short*)(ws + 8388608);     // 24 MiB (q|k|v)
  unsigned short* att   = (unsigned short*)(ws + 33554432);    // 8 MiB
  unsigned short* xt    = (unsigned short*)(ws + 41943040);    // 32 MiB
  unsigned short* w1b   = (unsigned short*)(ws + 75497472);    // 512 KiB
  unsigned short* wqkvb = (unsigned short*)(ws + 76021760);    // 384 KiB
  unsigned short* w3b   = (unsigned short*)(ws + 76414976);    // 512 KiB
  float*          sqkv  = (float*)(ws + 76939264);             // 3 KiB
  float*          bqkv  = (float*)(ws + 76942336);             // 3 KiB

  k_convert<<<dim3(2822), dim3(256), 0, stream>>>(
      w1, wq, wk, wv, w3, bnq_s, bnk_s, bnv_s, bnq_b, bnk_b, bnv_b,
      w1b, wqkvb, w3b, sqkv, bqkv);

  k_transpose_x<<<dim3(32, 32, 16), dim3(256), 0, stream>>>(x, xt);

  // conv1: M=256, N=16384, K=1024; tile 64x128 -> grid (128, 4)
  k_gemm_bt<2, 4, 0><<<dim3(128, 4), dim3(256), 0, stream>>>(
      w1b, xt, h1t, bn1_s, bn1_b, nullptr, 1024, 1);

  // fused qkv: stacked A (768x256); tile 128x128 -> grid (128, 6)
  k_gemm_bt<4, 4, 0><<<dim3(128, 6), dim3(256), 0, stream>>>(
      wqkvb, h1t, qkvt, sqkv, bqkv, nullptr, 256, 3);

  k_attn<<<dim3(2048), dim3(256), 0, stream>>>(
      qkvt, qkvt + 4194304, qkvt + 8388608, att, pos_h, pos_w, bnatt_s, bnatt_b);

  // conv3 + residual + relu -> d_out (f32); tile 128x64 -> grid (256, 8)
  k_gemm_bt<4, 2, 1><<<dim3(256, 8), dim3(256), 0, stream>>>(
      w3b, att, d_out, bn3_s, bn3_b, x, 256, 0);
}